// Round 5
// baseline (2673.649 us; speedup 1.0000x reference)
//
#include <hip/hip_runtime.h>

typedef __bf16 bf16x8 __attribute__((ext_vector_type(8)));
typedef float  f32x4  __attribute__((ext_vector_type(4)));

union U4 { uint4 u; bf16x8 v; };

__device__ __forceinline__ bf16x8 ld_frag(const void* p) {
    U4 t; t.u = *(const uint4*)p; return t.v;
}
__device__ __forceinline__ bf16x8 zfrag() {
    bf16x8 z;
#pragma unroll
    for (int jj = 0; jj < 8; jj++) z[jj] = (__bf16)0.f;
    return z;
}

__device__ __forceinline__ void gl_lds16(const uint4* g, void* l) {
    __builtin_amdgcn_global_load_lds(
        (const __attribute__((address_space(1))) unsigned int*)g,
        (__attribute__((address_space(3))) unsigned int*)l, 16, 0, 0);
}

__device__ __forceinline__ float sigf(float x) {
    return __builtin_amdgcn_rcpf(1.f + __expf(-x));
}
__device__ __forceinline__ float tanhf_fast(float x) {
    return 1.f - 2.f * __builtin_amdgcn_rcpf(1.f + __expf(2.f * x));
}

#define MFMA(A,B,C) C = __builtin_amdgcn_mfma_f32_16x16x32_bf16(A, B, C, 0, 0, 0)

// ---------------------------------------------------------------------------
// Pack [Wx (16 rows, pad to 32); Uh (256); Uh2 (256)] -> K=544 rows x 768 cols
// per direction, as B-fragments:
// pack[a][kt(17)][nt(48)][lane(64)] = 8 bf16 : B[kt*32+(lane>>4)*8+j][nt*16+(lane&15)]
// ---------------------------------------------------------------------------
__global__ void pack_kernel(const float* __restrict__ Wx, const float* __restrict__ Uh,
                            const float* __restrict__ Uh2, uint4* __restrict__ packW) {
    int tid = blockIdx.x * 256 + threadIdx.x;   // exactly 4*17*48*64 = 208896 threads
    int lane = tid & 63;
    int nt   = (tid >> 6) % 48;
    int kt   = ((tid >> 6) / 48) % 17;
    int a    = (tid >> 6) / (48 * 17);
    int col  = nt * 16 + (lane & 15);
    int kbase = kt * 32 + (lane >> 4) * 8;
    U4 u;
#pragma unroll
    for (int jj = 0; jj < 8; jj++) {
        int k = kbase + jj;
        float v;
        if (k < 16)       v = Wx[(a * 16 + k) * 768 + col];
        else if (k < 32)  v = 0.f;
        else if (k < 288) v = Uh[(a * 256 + (k - 32)) * 768 + col];
        else              v = Uh2[(a * 256 + (k - 288)) * 768 + col];
        u.v[jj] = (__bf16)v;
    }
    packW[tid] = u.u;
}

// ---------------------------------------------------------------------------
// Pack x patches into A-fragment layout:
// xpack[a][i(29)][j(29)][m(256)][q(2)] = uint4 (8 bf16): patch element k=q*8+jj
// ---------------------------------------------------------------------------
__global__ void xpack_kernel(const float* __restrict__ x, uint4* __restrict__ xp) {
    int tid = blockIdx.x * 256 + threadIdx.x;   // 4*29*29*256*2 = 1,722,368 threads
    int q = tid & 1;
    int m = (tid >> 1) & 255;
    int rem = tid >> 9;                          // a*841 + i*29 + j
    int j = rem % 29;
    int t2 = rem / 29;
    int i = t2 % 29;
    int a = t2 / 29;
    int Ny = 29 - (a & 1), Nx = 29 - ((a >> 1) & 1);
    U4 u;
    if (i < Ny && j < Nx) {
        int y0 = (a & 1) ? (27 - i) : i;
        int x0 = (a & 2) ? (27 - j) : j;
        const float* px = x + m * 1024 + y0 * 32 + x0;
#pragma unroll
        for (int jj = 0; jj < 8; jj++) {
            int k = q * 8 + jj;
            u.v[jj] = (__bf16)px[(k >> 2) * 32 + (k & 3)];
        }
    } else {
#pragma unroll
        for (int jj = 0; jj < 8; jj++) u.v[jj] = (__bf16)0.f;
    }
    xp[tid] = u.u;
}

// ---------------------------------------------------------------------------
// Wavefront kernel v5. Block = cell (a,i,j) x 32-hidden-col group g (0..7).
// 1 block/CU (launch_bounds 256,1). ALL 17 stages of B preloaded to dynamic LDS
// (17 x 6 KB = 104448 B) -> ONE barrier per block, no barriers in the K-loop.
// A-fragments rolling-prefetched 3 stages deep in registers.
// Stage order: s=0..7 hA (kt=s+1), s=8..15 hL (kt=s+1); x-stage uses LDS slot 16.
// XCD swizzle: bx = 8*slot + (2a + (j&1)); slot = cell_parity_idx*8 + g.
// hbuf layout (k-major per slice): [parity 2][a 4][j 29][kt 8][m 256][c32 32] bf16
// acc tiles: 0,1=r  2,3=z  4,5=n_h  6,7=n_x
// ---------------------------------------------------------------------------
__global__ __launch_bounds__(256, 1) void wf_kernel(
    const float* __restrict__ x, const uint4* __restrict__ xpack,
    const uint4* __restrict__ packW, const float* __restrict__ bias,
    __bf16* __restrict__ hbuf, int d, int4 jlo4, int4 jhi4)
{
    extern __shared__ __align__(16) unsigned char smem[];   // 104448 B

    int bx   = blockIdx.x;
    int xcd  = bx & 7;
    int a    = xcd >> 1;
    int p    = xcd & 1;
    int slot = bx >> 3;
    int g    = slot & 7;
    int ci   = slot >> 3;
    int lo = (a == 0) ? jlo4.x : (a == 1) ? jlo4.y : (a == 2) ? jlo4.z : jlo4.w;
    int hi = (a == 0) ? jhi4.x : (a == 1) ? jhi4.y : (a == 2) ? jhi4.z : jhi4.w;
    if (hi < lo) return;
    int j0 = lo + ((lo ^ p) & 1);
    int j  = j0 + 2 * ci;
    if (j > hi) return;
    int i = d - j;
    bool hasA = (i > 0);
    bool hasL = (j > 0);

    int tid  = threadIdx.x;
    int wm   = tid >> 6;
    int lane = tid & 63;
    int q    = lane >> 4;
    int l16  = lane & 15;

    int pprev = (d - 1) & 1;
    int pcur  = d & 1;
    const char* hAB = (const char*)(hbuf + ((size_t)(pprev * 4 + a) * 29 + j) * 65536);
    const char* hLB = (const char*)(hbuf + ((size_t)(pprev * 4 + a) * 29 + (j - 1)) * 65536);

    // ---- B preload: 102 chunks of 1 KB (17 stages x 6), split across 4 waves ----
    // LDS slot s (0..15 = h-stages, 16 = x-stage), chunk cc (0..5):
    //   addr = smem + (s*6+cc)*1024 ; src nt = (cc>>1)*16 + 2g + (cc&1), kt = s==16?0:s+1
    for (int c = wm; c < 102; c += 4) {
        int s  = c / 6;
        int cc = c - s * 6;
        int kt = (s == 16) ? 0 : (s + 1);
        int nt = (cc >> 1) * 16 + 2 * g + (cc & 1);
        gl_lds16(packW + (size_t)(a * 17 + kt) * 3072 + nt * 64 + lane,
                 smem + c * 1024);
    }

    f32x4 acc[4][8];
#pragma unroll
    for (int mt = 0; mt < 4; mt++)
#pragma unroll
        for (int tt = 0; tt < 8; tt++)
#pragma unroll
            for (int e = 0; e < 4; e++) acc[mt][tt][e] = 0.f;

    bf16x8 afp[4][4];   // rolling A-prefetch buffers
    auto issueA = [&](int s) {
        if (s >= 16) return;
        bool act = (s < 8) ? hasA : hasL;
        if (!act) return;
        const char* base = ((s < 8) ? hAB : hLB) + (s & 7) * 16384
                           + q * 16 + (wm * 64 + l16) * 64;
        bf16x8* dst = afp[s & 3];
#pragma unroll
        for (int mt = 0; mt < 4; mt++) dst[mt] = ld_frag(base + mt * 1024);
    };

    issueA(0); issueA(1); issueA(2);

    // x-stage A fragments (independent of LDS/barrier)
    bf16x8 afx[4];
    if (xpack) {
        const uint4* xpc = xpack + (size_t)((a * 29 + i) * 29 + j) * 512 + q;
#pragma unroll
        for (int mt = 0; mt < 4; mt++) {
            if (q < 2) afx[mt] = ld_frag(xpc + (wm * 64 + mt * 16 + l16) * 2);
            else       afx[mt] = zfrag();
        }
    } else {
        int y0 = (a & 1) ? (27 - i) : i;
        int x0 = (a & 2) ? (27 - j) : j;
#pragma unroll
        for (int mt = 0; mt < 4; mt++) {
            if (q < 2) {
                int m = wm * 64 + mt * 16 + l16;
                const float* xp = x + m * 1024 + (y0 + 2 * q) * 32 + x0;
#pragma unroll
                for (int jj = 0; jj < 8; jj++)
                    afx[mt][jj] = (__bf16)xp[(jj >> 2) * 32 + (jj & 3)];
            } else afx[mt] = zfrag();
        }
    }

    __syncthreads();    // the ONLY barrier: B fully resident in LDS after this

    // ---- x-stage compute: r,z -> acc 0..3 ; n_x -> acc 6,7 ----
    {
        const unsigned char* bb = smem + 16 * 6144 + lane * 16;
        bf16x8 b0 = ld_frag(bb + 0 * 1024);
        bf16x8 b1 = ld_frag(bb + 1 * 1024);
        bf16x8 b2 = ld_frag(bb + 2 * 1024);
        bf16x8 b3 = ld_frag(bb + 3 * 1024);
        bf16x8 b4 = ld_frag(bb + 4 * 1024);
        bf16x8 b5 = ld_frag(bb + 5 * 1024);
#pragma unroll
        for (int mt = 0; mt < 4; mt++) {
            MFMA(afx[mt], b0, acc[mt][0]); MFMA(afx[mt], b1, acc[mt][1]);
            MFMA(afx[mt], b2, acc[mt][2]); MFMA(afx[mt], b3, acc[mt][3]);
            MFMA(afx[mt], b4, acc[mt][6]); MFMA(afx[mt], b5, acc[mt][7]);
        }
    }

    // ---- 16 h-stages, no barriers, A prefetched 3 deep ----
#pragma unroll 4
    for (int s = 0; s < 16; ++s) {
        issueA(s + 3);
        bool act = (s < 8) ? hasA : hasL;
        if (act) {
            const unsigned char* bb = smem + s * 6144 + lane * 16;
            bf16x8 b0 = ld_frag(bb + 0 * 1024);
            bf16x8 b1 = ld_frag(bb + 1 * 1024);
            bf16x8 b2 = ld_frag(bb + 2 * 1024);
            bf16x8 b3 = ld_frag(bb + 3 * 1024);
            bf16x8 b4 = ld_frag(bb + 4 * 1024);
            bf16x8 b5 = ld_frag(bb + 5 * 1024);
            const bf16x8* af = afp[s & 3];
#pragma unroll
            for (int mt = 0; mt < 4; mt++) {
                MFMA(af[mt], b0, acc[mt][0]); MFMA(af[mt], b1, acc[mt][1]);
                MFMA(af[mt], b2, acc[mt][2]); MFMA(af[mt], b3, acc[mt][3]);
                MFMA(af[mt], b4, acc[mt][4]); MFMA(af[mt], b5, acc[mt][5]);
            }
        }
    }

    // ---- epilogue: gates + state update ----
    const float* ba = bias + a * 768;
    char* houtB = (char*)(hbuf + ((size_t)(pcur * 4 + a) * 29 + j) * 65536);
#pragma unroll
    for (int s = 0; s < 2; s++) {
        int c16 = s * 16 + l16;      // c & 31
        int c = g * 32 + c16;
        float bR = ba[c], bZ = ba[256 + c], bN = ba[512 + c];
#pragma unroll
        for (int mt = 0; mt < 4; mt++) {
#pragma unroll
            for (int r2 = 0; r2 < 4; r2++) {
                int m = wm * 64 + mt * 16 + q * 4 + r2;
                float rv = sigf(acc[mt][0 + s][r2] + bR);
                float zv = sigf(acc[mt][2 + s][r2] + bZ);
                float nv = tanhf_fast(acc[mt][6 + s][r2] + bN + rv * acc[mt][4 + s][r2]);
                size_t off = (size_t)g * 16384 + (size_t)m * 64 + c16 * 2;
                float hs = 0.f;
                if (hasA) hs += (float)(*(const __bf16*)(hAB + off));
                if (hasL) hs += (float)(*(const __bf16*)(hLB + off));
                *(__bf16*)(houtB + off) = (__bf16)((1.f - zv) * nv + 0.5f * zv * hs);
            }
        }
    }
}

// ---------------------------------------------------------------------------
// Output: logits = hcat @ W_out + b_out, then log_softmax. One wave per batch.
// hbuf slice layout is k-major: elem = (c>>5)*8192 + m*32 + (c&31)
// ---------------------------------------------------------------------------
__global__ __launch_bounds__(64) void out_kernel(const __bf16* __restrict__ hbuf,
    const float* __restrict__ Wout, const float* __restrict__ bout,
    float* __restrict__ out)
{
    int b = blockIdx.x;
    int tt = threadIdx.x;
    float accv[10];
#pragma unroll
    for (int o = 0; o < 10; o++) accv[o] = 0.f;
    for (int it = 0; it < 16; ++it) {
        int k = it * 64 + tt;
        int a = k >> 8, c = k & 255;
        int Ny = 29 - (a & 1), Nx = 29 - ((a >> 1) & 1);
        int pf = (Ny + Nx - 2) & 1;
        int jf = Nx - 1;
        float h = (float)hbuf[((size_t)(pf * 4 + a) * 29 + jf) * 65536
                              + (size_t)(c >> 5) * 8192 + (size_t)b * 32 + (c & 31)];
        const float* wr = Wout + k * 10;
#pragma unroll
        for (int o = 0; o < 10; o++) accv[o] += h * wr[o];
    }
#pragma unroll
    for (int off = 32; off > 0; off >>= 1)
#pragma unroll
        for (int o = 0; o < 10; o++) accv[o] += __shfl_down(accv[o], off, 64);
    if (tt == 0) {
        float l[10];
#pragma unroll
        for (int o = 0; o < 10; o++) l[o] = accv[o] + bout[o];
        float mx = l[0];
#pragma unroll
        for (int o = 1; o < 10; o++) mx = fmaxf(mx, l[o]);
        float se = 0.f;
#pragma unroll
        for (int o = 0; o < 10; o++) se += __expf(l[o] - mx);
        float lse = mx + __logf(se);
#pragma unroll
        for (int o = 0; o < 10; o++) out[b * 10 + o] = l[o] - lse;
    }
}

extern "C" void kernel_launch(void* const* d_in, const int* in_sizes, int n_in,
                              void* d_out, int out_size, void* d_ws, size_t ws_size,
                              hipStream_t stream) {
    const float* x    = (const float*)d_in[0];
    const float* Wx   = (const float*)d_in[1];
    const float* Uh   = (const float*)d_in[2];
    const float* Uh2  = (const float*)d_in[3];
    const float* b    = (const float*)d_in[4];
    const float* Wout = (const float*)d_in[5];
    const float* bout = (const float*)d_in[6];
    float* out = (float*)d_out;

    char* ws = (char*)d_ws;
    const size_t XPACK_OFF = 3407872;
    const size_t HBUF_OFF_BIG = 31457280;
    const size_t NEED = HBUF_OFF_BIG + 30408704;
    bool use_xp = (ws_size >= NEED);

    uint4*  packW = (uint4*)ws;
    uint4*  xpack = use_xp ? (uint4*)(ws + XPACK_OFF) : nullptr;
    __bf16* hbuf  = (__bf16*)(ws + (use_xp ? HBUF_OFF_BIG : XPACK_OFF));

    static bool attr_set = false;   // host-side only; idempotent, capture-safe
    (void)hipFuncSetAttribute((const void*)wf_kernel,
                              hipFuncAttributeMaxDynamicSharedMemorySize, 104448);

    pack_kernel<<<816, 256, 0, stream>>>(Wx, Uh, Uh2, packW);
    if (use_xp)
        xpack_kernel<<<6728, 256, 0, stream>>>(x, xpack);

    for (int d = 0; d < 57; ++d) {
        int jlo[4], jhi[4]; int maxslots = 0;
        for (int a = 0; a < 4; a++) {
            int Ny = 29 - (a & 1), Nx = 29 - ((a >> 1) & 1);
            int lo = d - (Ny - 1); if (lo < 0) lo = 0;
            int hi = (d < Nx - 1) ? d : Nx - 1;
            jlo[a] = lo; jhi[a] = hi;
            if (hi >= lo) {
                for (int p = 0; p < 2; p++) {
                    int j0 = lo + ((lo ^ p) & 1);
                    int c = (hi >= j0) ? ((hi - j0) >> 1) + 1 : 0;
                    if (c * 8 > maxslots) maxslots = c * 8;
                }
            }
        }
        int grid = 8 * maxslots;
        wf_kernel<<<grid, 256, 104448, stream>>>(x, xpack, packW, b, hbuf, d,
            make_int4(jlo[0], jlo[1], jlo[2], jlo[3]),
            make_int4(jhi[0], jhi[1], jhi[2], jhi[3]));
    }
    out_kernel<<<256, 64, 0, stream>>>(hbuf, Wout, bout, out);
}